// Round 15
// baseline (300.601 us; speedup 1.0000x reference)
//
#include <hip/hip_runtime.h>
#include <cmath>

#define GG 20000
#define NN 2048
#define PP 200
#define SS 128
#define EE 128
#define TN 128
#define TPP 4
#define NOCT 50

typedef __bf16 bf16x8 __attribute__((ext_vector_type(8)));
typedef float f32x16 __attribute__((ext_vector_type(16)));
typedef unsigned short u16x8 __attribute__((ext_vector_type(8)));

// static device scratch
__device__ __align__(16) unsigned g_xTi[(size_t)GG * NN];            // 164 MB (h | l<<16)
__device__ __align__(16) unsigned short g_Wsw[(size_t)PP * 32768];   // 13 MB pre-swizzled
__device__ float g_ctxp[(size_t)NN * NOCT * EE];                     // 52 MB quad partials
__device__ float g_mT[NOCT * NN];
__device__ float g_lT[NOCT * NN];
__device__ float g_statsp[6][64];

__device__ __forceinline__ unsigned short f2bf(float f) {
  unsigned u = __builtin_bit_cast(unsigned, f);
  return (unsigned short)((u + 0x7FFFu + ((u >> 16) & 1u)) >> 16);
}
__device__ __forceinline__ float bf2f(unsigned short h) {
  return __builtin_bit_cast(float, (unsigned)h << 16);
}
__device__ __forceinline__ unsigned packhl(float f) {
  unsigned short h = f2bf(f);
  unsigned short l = f2bf(f - bf2f(h));
  return (unsigned)h | ((unsigned)l << 16);
}

// ---------------------------------------------------------------------------
// Phase 0a: transpose x (2048 x 20000) -> xTi (20000 x 2048) interleaved hi/lo.
// ---------------------------------------------------------------------------
__global__ __launch_bounds__(256) void transpose_convert_kernel(
    const float* __restrict__ x)
{
  __shared__ unsigned tile[128 * 129];   // 66 KB
  const int g0 = blockIdx.x * 128;
  const int n0 = blockIdx.y * 128;
  const int t = threadIdx.x;

  {
    const int gq = t & 31, nr = t >> 5;
    const int g = g0 + gq * 4;
    #pragma unroll
    for (int k = 0; k < 16; ++k) {
      int nl = nr + 8 * k;
      unsigned v0 = 0, v1 = 0, v2 = 0, v3 = 0;
      if (g + 3 < GG) {
        float4 v = *(const float4*)&x[(size_t)(n0 + nl) * GG + g];
        v0 = packhl(v.x); v1 = packhl(v.y); v2 = packhl(v.z); v3 = packhl(v.w);
      }
      unsigned* row = &tile[nl * 129 + gq * 4];
      row[0] = v0; row[1] = v1; row[2] = v2; row[3] = v3;
    }
  }
  __syncthreads();
  {
    const int nq = t & 31, gr = t >> 5;
    #pragma unroll
    for (int k = 0; k < 16; ++k) {
      int gl = gr + 8 * k;
      int g = g0 + gl;
      if (g < GG) {
        uint4 o;
        o.x = tile[(nq * 4 + 0) * 129 + gl];
        o.y = tile[(nq * 4 + 1) * 129 + gl];
        o.z = tile[(nq * 4 + 2) * 129 + gl];
        o.w = tile[(nq * 4 + 3) * 129 + gl];
        *(uint4*)&g_xTi[(size_t)g * NN + n0 + nq * 4] = o;
      }
    }
  }
}

// ---------------------------------------------------------------------------
// Phase 0b: W_proj -> pre-swizzled bf16 hi/lo image (LDS-linear order).
// ---------------------------------------------------------------------------
__global__ __launch_bounds__(256) void wconvert_kernel(const float* __restrict__ Wp)
{
  unsigned v = blockIdx.x * 256 + threadIdx.x;   // [0, 200*16384)
  const int si = v & 7;
  const int slp = (v >> 3) & 7;
  const int e = (v >> 6) & 127;
  const int ch = (v >> 13) & 1;
  const int p = v >> 14;
  const int slot = slp ^ (e & 7);
  const int s = ch * 64 + slot * 8 + si;
  float f = Wp[((size_t)p * EE + e) * SS + s];
  unsigned short h = f2bf(f);
  unsigned short l = f2bf(f - bf2f(h));
  size_t base = (size_t)(p * 2 + ch) * 16384 + e * 64 + slp * 8 + si;
  g_Wsw[base] = h;
  g_Wsw[base + 8192] = l;
}

// ---------------------------------------------------------------------------
// Phase 0c: Wdec/bdec moment partials (64 blocks; final reduce in combine).
// ---------------------------------------------------------------------------
__global__ __launch_bounds__(256) void wdec_stats_partial(
    const float* __restrict__ Wdec, const float* __restrict__ bdec)
{
  __shared__ float red[6][4];
  const int b = blockIdx.x;                 // 64 blocks
  const int start = b * 313;
  const int end = (start + 313 < GG) ? start + 313 : GG;
  float s00 = 0, s11 = 0, s01 = 0, t0 = 0, t1 = 0, sbb = 0;
  for (int g = start + threadIdx.x; g < end; g += 256) {
    float w0 = Wdec[g], w1 = Wdec[GG + g], bb = bdec[g];
    s00 += w0 * w0; s11 += w1 * w1; s01 += w0 * w1;
    t0 += w0 * bb;  t1 += w1 * bb;  sbb += bb * bb;
  }
  #pragma unroll
  for (int off = 32; off >= 1; off >>= 1) {
    s00 += __shfl_xor(s00, off); s11 += __shfl_xor(s11, off);
    s01 += __shfl_xor(s01, off); t0 += __shfl_xor(t0, off);
    t1 += __shfl_xor(t1, off);   sbb += __shfl_xor(sbb, off);
  }
  const int w = threadIdx.x >> 6;
  if ((threadIdx.x & 63) == 0) {
    red[0][w] = s00; red[1][w] = s11; red[2][w] = s01;
    red[3][w] = t0;  red[4][w] = t1;  red[5][w] = sbb;
  }
  __syncthreads();
  if (threadIdx.x < 6)
    g_statsp[threadIdx.x][b] = red[threadIdx.x][0] + red[threadIdx.x][1] +
                               red[threadIdx.x][2] + red[threadIdx.x][3];
}

// ---------------------------------------------------------------------------
// proj helpers
// ---------------------------------------------------------------------------
__device__ __forceinline__ void load16(unsigned* xr, const int* sidx_lds,
                                       int sbase, int kh, int ncol) {
  #pragma unroll
  for (int ks2 = 0; ks2 < 2; ++ks2)
    #pragma unroll
    for (int j = 0; j < 8; ++j) {
      int s = (sbase + ks2) * 16 + kh * 8 + j;
      xr[ks2 * 8 + j] = g_xTi[(size_t)sidx_lds[s] * NN + ncol];
    }
}

// 2 chunk-local k-slices (ksl = klbase..+1) against the 32 KB chunk buffer
__device__ __forceinline__ void compute2ks(const unsigned short* wb,
                                           const unsigned* xr, f32x16 (&acc)[4],
                                           int klbase, int nl, int kh) {
  #pragma unroll
  for (int ks2 = 0; ks2 < 2; ++ks2) {
    const int ksl = klbase + ks2;
    const unsigned short* wAh = wb;
    const unsigned short* wAl = wb + 8192;
    u16x8 bhu, blu;
    #pragma unroll
    for (int j = 0; j < 8; ++j) {
      unsigned v = xr[ks2 * 8 + j];
      bhu[j] = (unsigned short)(v & 0xffffu);
      blu[j] = (unsigned short)(v >> 16);
    }
    bf16x8 bh = __builtin_bit_cast(bf16x8, bhu);
    bf16x8 bl = __builtin_bit_cast(bf16x8, blu);
    #pragma unroll
    for (int et = 0; et < 4; ++et) {
      const int e = et * 32 + nl;
      const int slp = (ksl * 2 + kh) ^ (e & 7);
      bf16x8 ah = __builtin_bit_cast(bf16x8, *(const uint4*)(wAh + e * 64 + slp * 8));
      bf16x8 al = __builtin_bit_cast(bf16x8, *(const uint4*)(wAl + e * 64 + slp * 8));
      acc[et] = __builtin_amdgcn_mfma_f32_32x32x16_bf16(ah, bh, acc[et], 0, 0, 0);
      acc[et] = __builtin_amdgcn_mfma_f32_32x32x16_bf16(ah, bl, acc[et], 0, 0, 0);
      acc[et] = __builtin_amdgcn_mfma_f32_32x32x16_bf16(al, bh, acc[et], 0, 0, 0);
    }
  }
}

// one full pathway, chunked W staging (32 KB buffer).  H left in h[].
__device__ __forceinline__ void pathway_body(
    int p, unsigned short* wbuf, int* sidx, float* sbp,
    const int* __restrict__ pidx, const float* __restrict__ bp,
    const float* __restrict__ tt, int tid_n,
    int t, int w, int ln, int nl, int kh, int ncol,
    f32x16 (&h)[4], float& s_out)
{
  #pragma unroll
  for (int et = 0; et < 4; ++et)
    #pragma unroll
    for (int r = 0; r < 16; ++r) h[et][r] = 0.f;

  #pragma unroll
  for (int ch = 0; ch < 2; ++ch) {
    __syncthreads();               // wbuf consumed by previous chunk/pathway
    if (ch == 0) {
      if (t < 128) sidx[t] = pidx[p * SS + t];
      else         sbp[t - 128] = bp[p * EE + (t - 128)];
    }
    // stage W chunk (32 KB): wave w stages shorts [w*4096, +4096)
    {
      const unsigned short* src = g_Wsw + (size_t)(p * 2 + ch) * 16384 + w * 4096 + ln * 8;
      unsigned short* dst = wbuf + w * 4096;   // wave-uniform; HW adds lane*16B
      #pragma unroll
      for (int j = 0; j < 8; ++j) {
        __builtin_amdgcn_global_load_lds(
            (const __attribute__((address_space(1))) unsigned int*)(src + j * 512),
            (__attribute__((address_space(3))) unsigned int*)(dst + j * 512), 16, 0, 0);
      }
    }
    __syncthreads();               // sidx/sbp visible + W chunk staged (drain)

    unsigned xa[16], xb[16];
    load16(xa, sidx, ch * 4 + 0, kh, ncol);
    load16(xb, sidx, ch * 4 + 2, kh, ncol);
    compute2ks(wbuf, xa, h, 0, nl, kh);
    compute2ks(wbuf, xb, h, 2, nl, kh);
  }

  // bias + relu + score (per-lane column n)
  const float4* qp = (const float4*)(tt + (size_t)tid_n * EE);
  float scr = 0.f;
  #pragma unroll
  for (int et = 0; et < 4; ++et)
    #pragma unroll
    for (int rq = 0; rq < 4; ++rq) {
      int e0 = et * 32 + rq * 8 + kh * 4;
      float4 q4 = qp[e0 >> 2];
      float4 b4 = *(const float4*)&sbp[e0];
      float h0 = fmaxf(h[et][rq * 4 + 0] + b4.x, 0.f);
      float h1 = fmaxf(h[et][rq * 4 + 1] + b4.y, 0.f);
      float h2 = fmaxf(h[et][rq * 4 + 2] + b4.z, 0.f);
      float h3 = fmaxf(h[et][rq * 4 + 3] + b4.w, 0.f);
      h[et][rq * 4 + 0] = h0; h[et][rq * 4 + 1] = h1;
      h[et][rq * 4 + 2] = h2; h[et][rq * 4 + 3] = h3;
      scr += h0 * q4.x + h1 * q4.y + h2 * q4.z + h3 * q4.w;
    }
  scr += __shfl_xor(scr, 32);
  s_out = scr * 0.08838834764831845f;   // 1/sqrt(128)
}

// ---------------------------------------------------------------------------
// Phase A: FOUR pathways per block, online-softmax in registers.
// grid (16, 50) = 800 blocks, block 256 (4 waves).  LDS 33 KB + VGPR 128
// -> 4 blocks/CU capacity; 800 blocks -> ~3.1 resident -> ~12 waves/CU.
// ---------------------------------------------------------------------------
__global__ __launch_bounds__(256, 2) void proj_mfma_kernel(
    const int* __restrict__ tidx, const int* __restrict__ pidx,
    const float* __restrict__ bp, const float* __restrict__ tt)
{
  __shared__ __align__(16) unsigned short wbuf[16384];   // 32 KB
  __shared__ int sidx[SS];
  __shared__ float sbp[EE];

  const int t = threadIdx.x;
  const int w = t >> 6;
  const int ln = t & 63;
  const int nl = ln & 31;
  const int kh = ln >> 5;
  const int n0 = blockIdx.x * TN;
  const int oct = blockIdx.y;
  const int ncol = n0 + w * 32 + nl;
  const int tid_n = tidx[ncol];

  f32x16 ctx[4];
  #pragma unroll
  for (int et = 0; et < 4; ++et)
    #pragma unroll
    for (int r = 0; r < 16; ++r) ctx[et][r] = 0.f;
  float m_r = -1e30f, l_r = 0.f;

  f32x16 h[4];
  float s;
  for (int pp = 0; pp < TPP; ++pp) {
    pathway_body(oct * TPP + pp, wbuf, sidx, sbp, pidx, bp, tt, tid_n,
                 t, w, ln, nl, kh, ncol, h, s);
    // online softmax update (exact fp32)
    const float mn = fmaxf(m_r, s);
    const float f = expf(m_r - mn);
    const float wg = expf(s - mn);
    l_r = l_r * f + wg;
    m_r = mn;
    #pragma unroll
    for (int et = 0; et < 4; ++et)
      #pragma unroll
      for (int r = 0; r < 16; ++r)
        ctx[et][r] = ctx[et][r] * f + wg * h[et][r];
  }

  // epilogue: LDS transpose in two 2-wave phases (32 KB buffer).
  __syncthreads();                 // all waves done reading wbuf
  float* tbase = (float*)wbuf;     // 8192 floats
  #pragma unroll
  for (int ph = 0; ph < 2; ++ph) {
    if ((w >> 1) == ph) {
      float* tb = tbase + (w & 1) * 4096;
      #pragma unroll
      for (int et = 0; et < 4; ++et)
        #pragma unroll
        for (int rq = 0; rq < 4; ++rq) {
          int slot = et * 8 + rq * 2 + kh;      // e-quad index 0..31
          float4 v = make_float4(ctx[et][rq * 4 + 0], ctx[et][rq * 4 + 1],
                                 ctx[et][rq * 4 + 2], ctx[et][rq * 4 + 3]);
          *(float4*)&tb[nl * 128 + ((slot ^ nl) << 2)] = v;
        }
      const int rrow = ln >> 1, eh = (ln & 1) * 16;
      const int nn = n0 + w * 32 + rrow;
      float* dst = g_ctxp + ((size_t)nn * NOCT + oct) * EE + eh * 4;
      const float* srcrow = tb + rrow * 128;
      #pragma unroll
      for (int k = 0; k < 16; ++k) {
        int slot = eh + k;
        *(float4*)&dst[k * 4] = *(const float4*)&srcrow[(slot ^ rrow) << 2];
      }
    }
    __syncthreads();
  }
  if (ln < 32) {
    g_mT[oct * NN + ncol] = m_r;
    g_lT[oct * NN + ncol] = l_r;
  }
}

// ---------------------------------------------------------------------------
// Phase B: merge 50 quad-partials + MLP + pcn/ang + closed-form norm + rec.
// grid 2048, block 256.
// ---------------------------------------------------------------------------
__global__ __launch_bounds__(256) void combine_rec_kernel(
    const float* __restrict__ W1, const float* __restrict__ b1,
    const float* __restrict__ W2, const float* __restrict__ b2,
    const float* __restrict__ Wdec, const float* __restrict__ bdec,
    float* __restrict__ out)
{
  const int n = blockIdx.x;
  const int t = threadIdx.x;
  __shared__ float ws[NOCT];
  __shared__ float ctx2[2][EE];
  __shared__ float r1[4], r2[4];
  __shared__ float hsh[32];
  __shared__ float qsh[3];
  __shared__ float stats_s[6];

  if (t >= 192 && t < 198) {       // spare threads: final stats reduce
    float v = 0.f;
    #pragma unroll 8
    for (int j = 0; j < 64; ++j) v += g_statsp[t - 192][j];
    stats_s[t - 192] = v;
  }

  float mv = (t < NOCT) ? g_mT[t * NN + n] : -1e30f;
  float lv = (t < NOCT) ? g_lT[t * NN + n] : 0.f;
  float M = mv;
  #pragma unroll
  for (int off = 32; off >= 1; off >>= 1) M = fmaxf(M, __shfl_xor(M, off));
  if ((t & 63) == 0) r1[t >> 6] = M;
  __syncthreads();
  M = fmaxf(fmaxf(r1[0], r1[1]), fmaxf(r1[2], r1[3]));
  float wv = (t < NOCT) ? expf(mv - M) : 0.f;
  if (t < NOCT) ws[t] = wv;
  float Lp = wv * lv;
  #pragma unroll
  for (int off = 32; off >= 1; off >>= 1) Lp += __shfl_xor(Lp, off);
  if ((t & 63) == 0) r2[t >> 6] = Lp;
  __syncthreads();               // ws visible + r2 ready
  const float L = r2[0] + r2[1] + r2[2] + r2[3];

  {
    const int e = t & 127, hf = t >> 7;
    const int sA = hf * 25;
    const float* base = g_ctxp + ((size_t)n * NOCT + sA) * EE + e;
    float c = 0.f;
    #pragma unroll 5
    for (int s = 0; s < 25; ++s) c += ws[sA + s] * base[(size_t)s * EE];
    ctx2[hf][e] = c;
  }
  __syncthreads();
  const float invL = 1.f / L;
  if (t < 32) {
    float h = 0.f;
    for (int e = 0; e < EE; ++e) h += (ctx2[0][e] + ctx2[1][e]) * W1[e * 32 + t];
    hsh[t] = fmaxf(h * invL + b1[t], 0.f);
  }
  __syncthreads();
  if (t == 0) {
    float p0 = b2[0], p1 = b2[1];
    #pragma unroll
    for (int k = 0; k < 32; ++k) { p0 += hsh[k] * W2[k * 2]; p1 += hsh[k] * W2[k * 2 + 1]; }
    float invp = 1.f / fmaxf(sqrtf(p0 * p0 + p1 * p1), 1e-12f);
    float q0 = p0 * invp, q1 = p1 * invp;
    const float PI2 = 6.2831853071795864769f;
    float ang = atan2f(q1, q0) + PI2;
    if (ang >= PI2) ang -= PI2;
    out[n * 2 + 0] = q0;
    out[n * 2 + 1] = q1;
    out[2 * NN + n] = ang;
    float n2 = q0 * q0 * stats_s[0] + q1 * q1 * stats_s[1] +
               2.f * q0 * q1 * stats_s[2] +
               2.f * q0 * stats_s[3] + 2.f * q1 * stats_s[4] + stats_s[5];
    qsh[0] = q0;
    qsh[1] = q1;
    qsh[2] = 1.f / fmaxf(sqrtf(n2), 1e-12f);
  }
  __syncthreads();
  const float q0 = qsh[0], q1 = qsh[1], inv = qsh[2];

  float* orec = out + 3 * NN + (size_t)n * GG;
  for (int i = t; i < GG / 4; i += 256) {
    float4 w0 = *(const float4*)&Wdec[i * 4];
    float4 w1 = *(const float4*)&Wdec[GG + i * 4];
    float4 b4 = *(const float4*)&bdec[i * 4];
    float4 o;
    o.x = (q0 * w0.x + q1 * w1.x + b4.x) * inv;
    o.y = (q0 * w0.y + q1 * w1.y + b4.y) * inv;
    o.z = (q0 * w0.z + q1 * w1.z + b4.z) * inv;
    o.w = (q0 * w0.w + q1 * w1.w + b4.w) * inv;
    *(float4*)&orec[i * 4] = o;
  }
}

// ---------------------------------------------------------------------------
extern "C" void kernel_launch(void* const* d_in, const int* in_sizes, int n_in,
                              void* d_out, int out_size, void* d_ws, size_t ws_size,
                              hipStream_t stream) {
  (void)in_sizes; (void)n_in; (void)out_size; (void)d_ws; (void)ws_size;
  const float* x    = (const float*)d_in[0];
  const int*   tidx = (const int*)  d_in[1];
  const int*   pidx = (const int*)  d_in[2];
  const float* Wp   = (const float*)d_in[3];
  const float* bp   = (const float*)d_in[4];
  const float* tt   = (const float*)d_in[5];
  const float* W1   = (const float*)d_in[6];
  const float* b1   = (const float*)d_in[7];
  const float* W2   = (const float*)d_in[8];
  const float* b2   = (const float*)d_in[9];
  const float* Wdec = (const float*)d_in[10];
  const float* bdec = (const float*)d_in[11];
  float* out = (float*)d_out;

  dim3 gridT((GG + 127) / 128, NN / 128, 1);   // 157 x 16
  transpose_convert_kernel<<<gridT, 256, 0, stream>>>(x);
  wconvert_kernel<<<(PP * 16384) / 256, 256, 0, stream>>>(Wp);
  wdec_stats_partial<<<64, 256, 0, stream>>>(Wdec, bdec);

  dim3 gridA(NN / TN, NOCT, 1);                // 16 x 50
  proj_mfma_kernel<<<gridA, 256, 0, stream>>>(tidx, pidx, bp, tt);

  combine_rec_kernel<<<NN, 256, 0, stream>>>(W1, b1, W2, b2, Wdec, bdec, out);
}

// Round 16
// 294.504 us; speedup vs baseline: 1.0207x; 1.0207x over previous
//
#include <hip/hip_runtime.h>
#include <cmath>

#define GG 20000
#define NN 2048
#define PP 200
#define SS 128
#define EE 128
#define TN 64
#define TPP 8
#define NOCT 25

typedef __bf16 bf16x8 __attribute__((ext_vector_type(8)));
typedef float f32x4 __attribute__((ext_vector_type(4)));
typedef unsigned short u16x8 __attribute__((ext_vector_type(8)));

// static device scratch
__device__ __align__(16) unsigned g_xTi[(size_t)GG * NN];            // 164 MB (h | l<<16)
__device__ __align__(16) unsigned short g_Wsw[(size_t)PP * 32768];   // 13 MB pre-swizzled
__device__ float g_ctxp[(size_t)NN * NOCT * EE];                     // 26 MB octet partials
__device__ float g_mT[NOCT * NN];
__device__ float g_lT[NOCT * NN];
__device__ float g_statsp[6][64];

__device__ __forceinline__ unsigned short f2bf(float f) {
  unsigned u = __builtin_bit_cast(unsigned, f);
  return (unsigned short)((u + 0x7FFFu + ((u >> 16) & 1u)) >> 16);
}
__device__ __forceinline__ float bf2f(unsigned short h) {
  return __builtin_bit_cast(float, (unsigned)h << 16);
}
__device__ __forceinline__ unsigned packhl(float f) {
  unsigned short h = f2bf(f);
  unsigned short l = f2bf(f - bf2f(h));
  return (unsigned)h | ((unsigned)l << 16);
}

// ---------------------------------------------------------------------------
// Phase 0a: transpose x (2048 x 20000) -> xTi (20000 x 2048) interleaved hi/lo.
// ---------------------------------------------------------------------------
__global__ __launch_bounds__(256) void transpose_convert_kernel(
    const float* __restrict__ x)
{
  __shared__ unsigned tile[128 * 129];   // 66 KB
  const int g0 = blockIdx.x * 128;
  const int n0 = blockIdx.y * 128;
  const int t = threadIdx.x;

  {
    const int gq = t & 31, nr = t >> 5;
    const int g = g0 + gq * 4;
    #pragma unroll
    for (int k = 0; k < 16; ++k) {
      int nl = nr + 8 * k;
      unsigned v0 = 0, v1 = 0, v2 = 0, v3 = 0;
      if (g + 3 < GG) {
        float4 v = *(const float4*)&x[(size_t)(n0 + nl) * GG + g];
        v0 = packhl(v.x); v1 = packhl(v.y); v2 = packhl(v.z); v3 = packhl(v.w);
      }
      unsigned* row = &tile[nl * 129 + gq * 4];
      row[0] = v0; row[1] = v1; row[2] = v2; row[3] = v3;
    }
  }
  __syncthreads();
  {
    const int nq = t & 31, gr = t >> 5;
    #pragma unroll
    for (int k = 0; k < 16; ++k) {
      int gl = gr + 8 * k;
      int g = g0 + gl;
      if (g < GG) {
        uint4 o;
        o.x = tile[(nq * 4 + 0) * 129 + gl];
        o.y = tile[(nq * 4 + 1) * 129 + gl];
        o.z = tile[(nq * 4 + 2) * 129 + gl];
        o.w = tile[(nq * 4 + 3) * 129 + gl];
        *(uint4*)&g_xTi[(size_t)g * NN + n0 + nq * 4] = o;
      }
    }
  }
}

// ---------------------------------------------------------------------------
// Phase 0b: W_proj -> pre-swizzled bf16 hi/lo image (LDS-linear order).
// Per (p,ch): h-block 8192 shorts then l-block; offset = e*64 + slp*8 + si
// holds W[p][e][ch*64 + (slp^(e&7))*8 + si].
// ---------------------------------------------------------------------------
__global__ __launch_bounds__(256) void wconvert_kernel(const float* __restrict__ Wp)
{
  unsigned v = blockIdx.x * 256 + threadIdx.x;   // [0, 200*16384)
  const int si = v & 7;
  const int slp = (v >> 3) & 7;
  const int e = (v >> 6) & 127;
  const int ch = (v >> 13) & 1;
  const int p = v >> 14;
  const int slot = slp ^ (e & 7);
  const int s = ch * 64 + slot * 8 + si;
  float f = Wp[((size_t)p * EE + e) * SS + s];
  unsigned short h = f2bf(f);
  unsigned short l = f2bf(f - bf2f(h));
  size_t base = (size_t)(p * 2 + ch) * 16384 + e * 64 + slp * 8 + si;
  g_Wsw[base] = h;
  g_Wsw[base + 8192] = l;
}

// ---------------------------------------------------------------------------
// Phase 0c: Wdec/bdec moment partials (64 blocks; final reduce in combine).
// ---------------------------------------------------------------------------
__global__ __launch_bounds__(256) void wdec_stats_partial(
    const float* __restrict__ Wdec, const float* __restrict__ bdec)
{
  __shared__ float red[6][4];
  const int b = blockIdx.x;                 // 64 blocks
  const int start = b * 313;
  const int end = (start + 313 < GG) ? start + 313 : GG;
  float s00 = 0, s11 = 0, s01 = 0, t0 = 0, t1 = 0, sbb = 0;
  for (int g = start + threadIdx.x; g < end; g += 256) {
    float w0 = Wdec[g], w1 = Wdec[GG + g], bb = bdec[g];
    s00 += w0 * w0; s11 += w1 * w1; s01 += w0 * w1;
    t0 += w0 * bb;  t1 += w1 * bb;  sbb += bb * bb;
  }
  #pragma unroll
  for (int off = 32; off >= 1; off >>= 1) {
    s00 += __shfl_xor(s00, off); s11 += __shfl_xor(s11, off);
    s01 += __shfl_xor(s01, off); t0 += __shfl_xor(t0, off);
    t1 += __shfl_xor(t1, off);   sbb += __shfl_xor(sbb, off);
  }
  const int w = threadIdx.x >> 6;
  if ((threadIdx.x & 63) == 0) {
    red[0][w] = s00; red[1][w] = s11; red[2][w] = s01;
    red[3][w] = t0;  red[4][w] = t1;  red[5][w] = sbb;
  }
  __syncthreads();
  if (threadIdx.x < 6)
    g_statsp[threadIdx.x][b] = red[threadIdx.x][0] + red[threadIdx.x][1] +
                               red[threadIdx.x][2] + red[threadIdx.x][3];
}

// ---------------------------------------------------------------------------
// Phase A: 16x16x32-MFMA projection, EIGHT pathways per block, online-softmax
// in registers.  grid (32, 25) = 800 blocks, block 256 (4 waves x 16 n-cols).
// Per-wave output 128e x 16n -> ctx 32 + h 32 regs; launch_bounds(256,3)
// caps regs at ~168 (no spill) -> 3 blocks/CU capacity.
// ---------------------------------------------------------------------------
__global__ __launch_bounds__(256, 3) void proj_mfma_kernel(
    const int* __restrict__ tidx, const int* __restrict__ pidx,
    const float* __restrict__ bp, const float* __restrict__ tt)
{
  __shared__ __align__(16) unsigned short wbuf[16384];   // 32 KB: hi 8192 | lo 8192
  __shared__ int sidx[SS];
  __shared__ float sbp[EE];

  const int t = threadIdx.x;
  const int w = t >> 6;
  const int ln = t & 63;
  const int c = ln & 15;          // n-col within wave (also A-row within e-tile)
  const int q = ln >> 4;          // k-octet group 0..3
  const int n0 = blockIdx.x * TN;
  const int oct = blockIdx.y;
  const int ncol = n0 + w * 16 + c;
  const int tid_n = tidx[ncol];

  f32x4 ctx[8];
  #pragma unroll
  for (int t8 = 0; t8 < 8; ++t8)
    #pragma unroll
    for (int r = 0; r < 4; ++r) ctx[t8][r] = 0.f;
  float m_r = -1e30f, l_r = 0.f;

  for (int pp = 0; pp < TPP; ++pp) {
    const int p = oct * TPP + pp;
    f32x4 h[8];
    #pragma unroll
    for (int t8 = 0; t8 < 8; ++t8)
      #pragma unroll
      for (int r = 0; r < 4; ++r) h[t8][r] = 0.f;

    #pragma unroll
    for (int ch = 0; ch < 2; ++ch) {
      __syncthreads();             // wbuf consumed by previous chunk/pathway
      if (ch == 0) {
        if (t < 128) sidx[t] = pidx[p * SS + t];
        else         sbp[t - 128] = bp[p * EE + (t - 128)];
      }
      // stage W chunk (32 KB): wave w stages shorts [w*4096, +4096)
      {
        const unsigned short* src = g_Wsw + (size_t)(p * 2 + ch) * 16384 + w * 4096 + ln * 8;
        unsigned short* dst = wbuf + w * 4096;   // wave-uniform; HW adds lane*16B
        #pragma unroll
        for (int j = 0; j < 8; ++j) {
          __builtin_amdgcn_global_load_lds(
              (const __attribute__((address_space(1))) unsigned int*)(src + j * 512),
              (__attribute__((address_space(3))) unsigned int*)(dst + j * 512), 16, 0, 0);
        }
      }
      __syncthreads();             // sidx/sbp visible + W chunk staged (drain)

      #pragma unroll
      for (int ks = 0; ks < 2; ++ks) {
        const int sb = ch * 64 + ks * 32 + q * 8;
        u16x8 bhu, blu;
        #pragma unroll
        for (int j = 0; j < 8; ++j) {
          unsigned v = g_xTi[(size_t)sidx[sb + j] * NN + ncol];
          bhu[j] = (unsigned short)(v & 0xffffu);
          blu[j] = (unsigned short)(v >> 16);
        }
        bf16x8 bh = __builtin_bit_cast(bf16x8, bhu);
        bf16x8 bl = __builtin_bit_cast(bf16x8, blu);
        const int slp = (ks * 4 + q) ^ (c & 7);   // e&7 == c&7 (t8*16 = 0 mod 8)
        #pragma unroll
        for (int t8 = 0; t8 < 8; ++t8) {
          const int e = t8 * 16 + c;
          bf16x8 ah = __builtin_bit_cast(bf16x8, *(const uint4*)(wbuf + e * 64 + slp * 8));
          bf16x8 al = __builtin_bit_cast(bf16x8, *(const uint4*)(wbuf + 8192 + e * 64 + slp * 8));
          h[t8] = __builtin_amdgcn_mfma_f32_16x16x32_bf16(ah, bh, h[t8], 0, 0, 0);
          h[t8] = __builtin_amdgcn_mfma_f32_16x16x32_bf16(ah, bl, h[t8], 0, 0, 0);
          h[t8] = __builtin_amdgcn_mfma_f32_16x16x32_bf16(al, bh, h[t8], 0, 0, 0);
        }
      }
    }

    // bias + relu + score (lane owns e = t8*16 + q*4 + r for col ncol)
    const float4* qp = (const float4*)(tt + (size_t)tid_n * EE);
    float scr = 0.f;
    #pragma unroll
    for (int t8 = 0; t8 < 8; ++t8) {
      const int e0 = t8 * 16 + q * 4;
      float4 q4 = qp[e0 >> 2];
      float4 b4 = *(const float4*)&sbp[e0];
      float h0 = fmaxf(h[t8][0] + b4.x, 0.f);
      float h1 = fmaxf(h[t8][1] + b4.y, 0.f);
      float h2 = fmaxf(h[t8][2] + b4.z, 0.f);
      float h3 = fmaxf(h[t8][3] + b4.w, 0.f);
      h[t8][0] = h0; h[t8][1] = h1; h[t8][2] = h2; h[t8][3] = h3;
      scr += h0 * q4.x + h1 * q4.y + h2 * q4.z + h3 * q4.w;
    }
    scr += __shfl_xor(scr, 16);
    scr += __shfl_xor(scr, 32);
    const float s_r = scr * 0.08838834764831845f;   // 1/sqrt(128)

    // online softmax update (exact fp32)
    const float mn = fmaxf(m_r, s_r);
    const float f = expf(m_r - mn);
    const float wg = expf(s_r - mn);
    l_r = l_r * f + wg;
    m_r = mn;
    #pragma unroll
    for (int t8 = 0; t8 < 8; ++t8)
      #pragma unroll
      for (int r = 0; r < 4; ++r)
        ctx[t8][r] = ctx[t8][r] * f + wg * h[t8][r];
  }

  // epilogue: direct f32x4 stores (26 MB logical; scatter harmless)
  float* dst = g_ctxp + ((size_t)ncol * NOCT + oct) * EE;
  #pragma unroll
  for (int t8 = 0; t8 < 8; ++t8)
    *(f32x4*)&dst[t8 * 16 + q * 4] = ctx[t8];
  if (ln < 16) {
    g_mT[oct * NN + ncol] = m_r;
    g_lT[oct * NN + ncol] = l_r;
  }
}

// ---------------------------------------------------------------------------
// Phase B: merge 25 octet-partials + MLP + pcn/ang + closed-form norm + rec.
// grid 2048, block 256.
// ---------------------------------------------------------------------------
__global__ __launch_bounds__(256) void combine_rec_kernel(
    const float* __restrict__ W1, const float* __restrict__ b1,
    const float* __restrict__ W2, const float* __restrict__ b2,
    const float* __restrict__ Wdec, const float* __restrict__ bdec,
    float* __restrict__ out)
{
  const int n = blockIdx.x;
  const int t = threadIdx.x;
  __shared__ float ws[NOCT];
  __shared__ float ctx2[2][EE];
  __shared__ float r1[4], r2[4];
  __shared__ float hsh[32];
  __shared__ float qsh[3];
  __shared__ float stats_s[6];

  if (t >= 192 && t < 198) {       // spare threads: final stats reduce
    float v = 0.f;
    #pragma unroll 8
    for (int j = 0; j < 64; ++j) v += g_statsp[t - 192][j];
    stats_s[t - 192] = v;
  }

  float mv = (t < NOCT) ? g_mT[t * NN + n] : -1e30f;
  float lv = (t < NOCT) ? g_lT[t * NN + n] : 0.f;
  float M = mv;
  #pragma unroll
  for (int off = 32; off >= 1; off >>= 1) M = fmaxf(M, __shfl_xor(M, off));
  if ((t & 63) == 0) r1[t >> 6] = M;
  __syncthreads();
  M = fmaxf(fmaxf(r1[0], r1[1]), fmaxf(r1[2], r1[3]));
  float wv = (t < NOCT) ? expf(mv - M) : 0.f;
  if (t < NOCT) ws[t] = wv;
  float Lp = wv * lv;
  #pragma unroll
  for (int off = 32; off >= 1; off >>= 1) Lp += __shfl_xor(Lp, off);
  if ((t & 63) == 0) r2[t >> 6] = Lp;
  __syncthreads();               // ws visible + r2 ready
  const float L = r2[0] + r2[1] + r2[2] + r2[3];

  {
    const int e = t & 127, hf = t >> 7;
    const int sA = hf ? 13 : 0, sB = hf ? NOCT : 13;
    const float* base = g_ctxp + ((size_t)n * NOCT + sA) * EE + e;
    float c = 0.f;
    for (int s = sA; s < sB; ++s) c += ws[s] * base[(size_t)(s - sA) * EE];
    ctx2[hf][e] = c;
  }
  __syncthreads();
  const float invL = 1.f / L;
  if (t < 32) {
    float h = 0.f;
    for (int e = 0; e < EE; ++e) h += (ctx2[0][e] + ctx2[1][e]) * W1[e * 32 + t];
    hsh[t] = fmaxf(h * invL + b1[t], 0.f);
  }
  __syncthreads();
  if (t == 0) {
    float p0 = b2[0], p1 = b2[1];
    #pragma unroll
    for (int k = 0; k < 32; ++k) { p0 += hsh[k] * W2[k * 2]; p1 += hsh[k] * W2[k * 2 + 1]; }
    float invp = 1.f / fmaxf(sqrtf(p0 * p0 + p1 * p1), 1e-12f);
    float q0 = p0 * invp, q1 = p1 * invp;
    const float PI2 = 6.2831853071795864769f;
    float ang = atan2f(q1, q0) + PI2;
    if (ang >= PI2) ang -= PI2;
    out[n * 2 + 0] = q0;
    out[n * 2 + 1] = q1;
    out[2 * NN + n] = ang;
    float n2 = q0 * q0 * stats_s[0] + q1 * q1 * stats_s[1] +
               2.f * q0 * q1 * stats_s[2] +
               2.f * q0 * stats_s[3] + 2.f * q1 * stats_s[4] + stats_s[5];
    qsh[0] = q0;
    qsh[1] = q1;
    qsh[2] = 1.f / fmaxf(sqrtf(n2), 1e-12f);
  }
  __syncthreads();
  const float q0 = qsh[0], q1 = qsh[1], inv = qsh[2];

  float* orec = out + 3 * NN + (size_t)n * GG;
  for (int i = t; i < GG / 4; i += 256) {
    float4 w0 = *(const float4*)&Wdec[i * 4];
    float4 w1 = *(const float4*)&Wdec[GG + i * 4];
    float4 b4 = *(const float4*)&bdec[i * 4];
    float4 o;
    o.x = (q0 * w0.x + q1 * w1.x + b4.x) * inv;
    o.y = (q0 * w0.y + q1 * w1.y + b4.y) * inv;
    o.z = (q0 * w0.z + q1 * w1.z + b4.z) * inv;
    o.w = (q0 * w0.w + q1 * w1.w + b4.w) * inv;
    *(float4*)&orec[i * 4] = o;
  }
}

// ---------------------------------------------------------------------------
extern "C" void kernel_launch(void* const* d_in, const int* in_sizes, int n_in,
                              void* d_out, int out_size, void* d_ws, size_t ws_size,
                              hipStream_t stream) {
  (void)in_sizes; (void)n_in; (void)out_size; (void)d_ws; (void)ws_size;
  const float* x    = (const float*)d_in[0];
  const int*   tidx = (const int*)  d_in[1];
  const int*   pidx = (const int*)  d_in[2];
  const float* Wp   = (const float*)d_in[3];
  const float* bp   = (const float*)d_in[4];
  const float* tt   = (const float*)d_in[5];
  const float* W1   = (const float*)d_in[6];
  const float* b1   = (const float*)d_in[7];
  const float* W2   = (const float*)d_in[8];
  const float* b2   = (const float*)d_in[9];
  const float* Wdec = (const float*)d_in[10];
  const float* bdec = (const float*)d_in[11];
  float* out = (float*)d_out;

  dim3 gridT((GG + 127) / 128, NN / 128, 1);   // 157 x 16
  transpose_convert_kernel<<<gridT, 256, 0, stream>>>(x);
  wconvert_kernel<<<(PP * 16384) / 256, 256, 0, stream>>>(Wp);
  wdec_stats_partial<<<64, 256, 0, stream>>>(Wdec, bdec);

  dim3 gridA(NN / TN, NOCT, 1);                // 32 x 25
  proj_mfma_kernel<<<gridA, 256, 0, stream>>>(tidx, pidx, bp, tt);

  combine_rec_kernel<<<NN, 256, 0, stream>>>(W1, b1, W2, b2, Wdec, bdec, out);
}

// Round 17
// 289.664 us; speedup vs baseline: 1.0378x; 1.0167x over previous
//
#include <hip/hip_runtime.h>
#include <cmath>

#define GG 20000
#define NN 2048
#define PP 200
#define SS 128
#define EE 128
#define TN 128
#define TPP 8
#define NOCT 25

typedef __bf16 bf16x8 __attribute__((ext_vector_type(8)));
typedef float f32x4 __attribute__((ext_vector_type(4)));
typedef unsigned short u16x8 __attribute__((ext_vector_type(8)));

// static device scratch
__device__ __align__(16) unsigned g_xTi[(size_t)GG * NN];            // 164 MB (h | l<<16)
__device__ __align__(16) unsigned short g_Wsw[(size_t)PP * 32768];   // 13 MB pre-swizzled
__device__ float g_ctxp[(size_t)NN * NOCT * EE];                     // 26 MB octet partials
__device__ float g_mT[NOCT * NN];
__device__ float g_lT[NOCT * NN];
__device__ float g_statsp[6][64];

__device__ __forceinline__ unsigned short f2bf(float f) {
  unsigned u = __builtin_bit_cast(unsigned, f);
  return (unsigned short)((u + 0x7FFFu + ((u >> 16) & 1u)) >> 16);
}
__device__ __forceinline__ float bf2f(unsigned short h) {
  return __builtin_bit_cast(float, (unsigned)h << 16);
}
__device__ __forceinline__ unsigned packhl(float f) {
  unsigned short h = f2bf(f);
  unsigned short l = f2bf(f - bf2f(h));
  return (unsigned)h | ((unsigned)l << 16);
}

// ---------------------------------------------------------------------------
// Phase 0a: transpose x (2048 x 20000) -> xTi (20000 x 2048) interleaved hi/lo.
// ---------------------------------------------------------------------------
__global__ __launch_bounds__(256) void transpose_convert_kernel(
    const float* __restrict__ x)
{
  __shared__ unsigned tile[128 * 129];   // 66 KB
  const int g0 = blockIdx.x * 128;
  const int n0 = blockIdx.y * 128;
  const int t = threadIdx.x;

  {
    const int gq = t & 31, nr = t >> 5;
    const int g = g0 + gq * 4;
    #pragma unroll
    for (int k = 0; k < 16; ++k) {
      int nl = nr + 8 * k;
      unsigned v0 = 0, v1 = 0, v2 = 0, v3 = 0;
      if (g + 3 < GG) {
        float4 v = *(const float4*)&x[(size_t)(n0 + nl) * GG + g];
        v0 = packhl(v.x); v1 = packhl(v.y); v2 = packhl(v.z); v3 = packhl(v.w);
      }
      unsigned* row = &tile[nl * 129 + gq * 4];
      row[0] = v0; row[1] = v1; row[2] = v2; row[3] = v3;
    }
  }
  __syncthreads();
  {
    const int nq = t & 31, gr = t >> 5;
    #pragma unroll
    for (int k = 0; k < 16; ++k) {
      int gl = gr + 8 * k;
      int g = g0 + gl;
      if (g < GG) {
        uint4 o;
        o.x = tile[(nq * 4 + 0) * 129 + gl];
        o.y = tile[(nq * 4 + 1) * 129 + gl];
        o.z = tile[(nq * 4 + 2) * 129 + gl];
        o.w = tile[(nq * 4 + 3) * 129 + gl];
        *(uint4*)&g_xTi[(size_t)g * NN + n0 + nq * 4] = o;
      }
    }
  }
}

// ---------------------------------------------------------------------------
// Phase 0b: W_proj -> pre-swizzled bf16 hi/lo image (LDS-linear order).
// Per (p,ch): h-block 8192 shorts then l-block; offset = e*64 + slp*8 + si
// holds W[p][e][ch*64 + (slp^(e&7))*8 + si].
// ---------------------------------------------------------------------------
__global__ __launch_bounds__(256) void wconvert_kernel(const float* __restrict__ Wp)
{
  unsigned v = blockIdx.x * 256 + threadIdx.x;   // [0, 200*16384)
  const int si = v & 7;
  const int slp = (v >> 3) & 7;
  const int e = (v >> 6) & 127;
  const int ch = (v >> 13) & 1;
  const int p = v >> 14;
  const int slot = slp ^ (e & 7);
  const int s = ch * 64 + slot * 8 + si;
  float f = Wp[((size_t)p * EE + e) * SS + s];
  unsigned short h = f2bf(f);
  unsigned short l = f2bf(f - bf2f(h));
  size_t base = (size_t)(p * 2 + ch) * 16384 + e * 64 + slp * 8 + si;
  g_Wsw[base] = h;
  g_Wsw[base + 8192] = l;
}

// ---------------------------------------------------------------------------
// Phase 0c: Wdec/bdec moment partials (64 blocks; final reduce in combine).
// ---------------------------------------------------------------------------
__global__ __launch_bounds__(256) void wdec_stats_partial(
    const float* __restrict__ Wdec, const float* __restrict__ bdec)
{
  __shared__ float red[6][4];
  const int b = blockIdx.x;                 // 64 blocks
  const int start = b * 313;
  const int end = (start + 313 < GG) ? start + 313 : GG;
  float s00 = 0, s11 = 0, s01 = 0, t0 = 0, t1 = 0, sbb = 0;
  for (int g = start + threadIdx.x; g < end; g += 256) {
    float w0 = Wdec[g], w1 = Wdec[GG + g], bb = bdec[g];
    s00 += w0 * w0; s11 += w1 * w1; s01 += w0 * w1;
    t0 += w0 * bb;  t1 += w1 * bb;  sbb += bb * bb;
  }
  #pragma unroll
  for (int off = 32; off >= 1; off >>= 1) {
    s00 += __shfl_xor(s00, off); s11 += __shfl_xor(s11, off);
    s01 += __shfl_xor(s01, off); t0 += __shfl_xor(t0, off);
    t1 += __shfl_xor(t1, off);   sbb += __shfl_xor(sbb, off);
  }
  const int w = threadIdx.x >> 6;
  if ((threadIdx.x & 63) == 0) {
    red[0][w] = s00; red[1][w] = s11; red[2][w] = s01;
    red[3][w] = t0;  red[4][w] = t1;  red[5][w] = sbb;
  }
  __syncthreads();
  if (threadIdx.x < 6)
    g_statsp[threadIdx.x][b] = red[threadIdx.x][0] + red[threadIdx.x][1] +
                               red[threadIdx.x][2] + red[threadIdx.x][3];
}

// ---------------------------------------------------------------------------
// Phase A: 16x16x32-MFMA projection, EIGHT pathways per block, online-softmax
// in registers.  grid (16, 25) = 400 blocks, block 512 (8 waves x 16 n-cols
// = TN 128).  8 waves read the SAME gather rows at adjacent 64B offsets ->
// full 512B line-sets in L2 (kills the r16 64B-segment overfetch).
// ---------------------------------------------------------------------------
__global__ __launch_bounds__(512, 3) void proj_mfma_kernel(
    const int* __restrict__ tidx, const int* __restrict__ pidx,
    const float* __restrict__ bp, const float* __restrict__ tt)
{
  __shared__ __align__(16) unsigned short wbuf[16384];   // 32 KB: hi 8192 | lo 8192
  __shared__ int sidx[SS];
  __shared__ float sbp[EE];

  const int t = threadIdx.x;
  const int w = t >> 6;           // 0..7
  const int ln = t & 63;
  const int c = ln & 15;          // n-col within wave (also A-row within e-tile)
  const int q = ln >> 4;          // k-octet group 0..3
  const int n0 = blockIdx.x * TN;
  const int oct = blockIdx.y;
  const int ncol = n0 + w * 16 + c;
  const int tid_n = tidx[ncol];

  f32x4 ctx[8];
  #pragma unroll
  for (int t8 = 0; t8 < 8; ++t8)
    #pragma unroll
    for (int r = 0; r < 4; ++r) ctx[t8][r] = 0.f;
  float m_r = -1e30f, l_r = 0.f;

  for (int pp = 0; pp < TPP; ++pp) {
    const int p = oct * TPP + pp;
    f32x4 h[8];
    #pragma unroll
    for (int t8 = 0; t8 < 8; ++t8)
      #pragma unroll
      for (int r = 0; r < 4; ++r) h[t8][r] = 0.f;

    #pragma unroll
    for (int ch = 0; ch < 2; ++ch) {
      __syncthreads();             // wbuf consumed by previous chunk/pathway
      if (ch == 0) {
        if (t < 128) sidx[t] = pidx[p * SS + t];
        else if (t < 256) sbp[t - 128] = bp[p * EE + (t - 128)];
      }
      // stage W chunk (32 KB): wave w stages shorts [w*2048, +2048)
      {
        const unsigned short* src = g_Wsw + (size_t)(p * 2 + ch) * 16384 + w * 2048 + ln * 8;
        unsigned short* dst = wbuf + w * 2048;   // wave-uniform; HW adds lane*16B
        #pragma unroll
        for (int j = 0; j < 4; ++j) {
          __builtin_amdgcn_global_load_lds(
              (const __attribute__((address_space(1))) unsigned int*)(src + j * 512),
              (__attribute__((address_space(3))) unsigned int*)(dst + j * 512), 16, 0, 0);
        }
      }
      __syncthreads();             // sidx/sbp visible + W chunk staged (drain)

      #pragma unroll
      for (int ks = 0; ks < 2; ++ks) {
        const int sb = ch * 64 + ks * 32 + q * 8;
        u16x8 bhu, blu;
        #pragma unroll
        for (int j = 0; j < 8; ++j) {
          unsigned v = g_xTi[(size_t)sidx[sb + j] * NN + ncol];
          bhu[j] = (unsigned short)(v & 0xffffu);
          blu[j] = (unsigned short)(v >> 16);
        }
        bf16x8 bh = __builtin_bit_cast(bf16x8, bhu);
        bf16x8 bl = __builtin_bit_cast(bf16x8, blu);
        const int slp = (ks * 4 + q) ^ (c & 7);   // e&7 == c&7 (t8*16 = 0 mod 8)
        #pragma unroll
        for (int t8 = 0; t8 < 8; ++t8) {
          const int e = t8 * 16 + c;
          bf16x8 ah = __builtin_bit_cast(bf16x8, *(const uint4*)(wbuf + e * 64 + slp * 8));
          bf16x8 al = __builtin_bit_cast(bf16x8, *(const uint4*)(wbuf + 8192 + e * 64 + slp * 8));
          h[t8] = __builtin_amdgcn_mfma_f32_16x16x32_bf16(ah, bh, h[t8], 0, 0, 0);
          h[t8] = __builtin_amdgcn_mfma_f32_16x16x32_bf16(ah, bl, h[t8], 0, 0, 0);
          h[t8] = __builtin_amdgcn_mfma_f32_16x16x32_bf16(al, bh, h[t8], 0, 0, 0);
        }
      }
    }

    // bias + relu + score (lane owns e = t8*16 + q*4 + r for col ncol)
    const float4* qp = (const float4*)(tt + (size_t)tid_n * EE);
    float scr = 0.f;
    #pragma unroll
    for (int t8 = 0; t8 < 8; ++t8) {
      const int e0 = t8 * 16 + q * 4;
      float4 q4 = qp[e0 >> 2];
      float4 b4 = *(const float4*)&sbp[e0];
      float h0 = fmaxf(h[t8][0] + b4.x, 0.f);
      float h1 = fmaxf(h[t8][1] + b4.y, 0.f);
      float h2 = fmaxf(h[t8][2] + b4.z, 0.f);
      float h3 = fmaxf(h[t8][3] + b4.w, 0.f);
      h[t8][0] = h0; h[t8][1] = h1; h[t8][2] = h2; h[t8][3] = h3;
      scr += h0 * q4.x + h1 * q4.y + h2 * q4.z + h3 * q4.w;
    }
    scr += __shfl_xor(scr, 16);
    scr += __shfl_xor(scr, 32);
    const float s_r = scr * 0.08838834764831845f;   // 1/sqrt(128)

    // online softmax update (exact fp32)
    const float mn = fmaxf(m_r, s_r);
    const float f = expf(m_r - mn);
    const float wg = expf(s_r - mn);
    l_r = l_r * f + wg;
    m_r = mn;
    #pragma unroll
    for (int t8 = 0; t8 < 8; ++t8)
      #pragma unroll
      for (int r = 0; r < 4; ++r)
        ctx[t8][r] = ctx[t8][r] * f + wg * h[t8][r];
  }

  // epilogue: direct f32x4 stores (26 MB logical; scatter harmless)
  float* dst = g_ctxp + ((size_t)ncol * NOCT + oct) * EE;
  #pragma unroll
  for (int t8 = 0; t8 < 8; ++t8)
    *(f32x4*)&dst[t8 * 16 + q * 4] = ctx[t8];
  if (ln < 16) {
    g_mT[oct * NN + ncol] = m_r;
    g_lT[oct * NN + ncol] = l_r;
  }
}

// ---------------------------------------------------------------------------
// Phase B: merge 25 octet-partials + MLP + pcn/ang + closed-form norm + rec.
// grid 2048, block 256.
// ---------------------------------------------------------------------------
__global__ __launch_bounds__(256) void combine_rec_kernel(
    const float* __restrict__ W1, const float* __restrict__ b1,
    const float* __restrict__ W2, const float* __restrict__ b2,
    const float* __restrict__ Wdec, const float* __restrict__ bdec,
    float* __restrict__ out)
{
  const int n = blockIdx.x;
  const int t = threadIdx.x;
  __shared__ float ws[NOCT];
  __shared__ float ctx2[2][EE];
  __shared__ float r1[4], r2[4];
  __shared__ float hsh[32];
  __shared__ float qsh[3];
  __shared__ float stats_s[6];

  if (t >= 192 && t < 198) {       // spare threads: final stats reduce
    float v = 0.f;
    #pragma unroll 8
    for (int j = 0; j < 64; ++j) v += g_statsp[t - 192][j];
    stats_s[t - 192] = v;
  }

  float mv = (t < NOCT) ? g_mT[t * NN + n] : -1e30f;
  float lv = (t < NOCT) ? g_lT[t * NN + n] : 0.f;
  float M = mv;
  #pragma unroll
  for (int off = 32; off >= 1; off >>= 1) M = fmaxf(M, __shfl_xor(M, off));
  if ((t & 63) == 0) r1[t >> 6] = M;
  __syncthreads();
  M = fmaxf(fmaxf(r1[0], r1[1]), fmaxf(r1[2], r1[3]));
  float wv = (t < NOCT) ? expf(mv - M) : 0.f;
  if (t < NOCT) ws[t] = wv;
  float Lp = wv * lv;
  #pragma unroll
  for (int off = 32; off >= 1; off >>= 1) Lp += __shfl_xor(Lp, off);
  if ((t & 63) == 0) r2[t >> 6] = Lp;
  __syncthreads();               // ws visible + r2 ready
  const float L = r2[0] + r2[1] + r2[2] + r2[3];

  {
    const int e = t & 127, hf = t >> 7;
    const int sA = hf ? 13 : 0, sB = hf ? NOCT : 13;
    const float* base = g_ctxp + ((size_t)n * NOCT + sA) * EE + e;
    float c = 0.f;
    for (int s = sA; s < sB; ++s) c += ws[s] * base[(size_t)(s - sA) * EE];
    ctx2[hf][e] = c;
  }
  __syncthreads();
  const float invL = 1.f / L;
  if (t < 32) {
    float h = 0.f;
    for (int e = 0; e < EE; ++e) h += (ctx2[0][e] + ctx2[1][e]) * W1[e * 32 + t];
    hsh[t] = fmaxf(h * invL + b1[t], 0.f);
  }
  __syncthreads();
  if (t == 0) {
    float p0 = b2[0], p1 = b2[1];
    #pragma unroll
    for (int k = 0; k < 32; ++k) { p0 += hsh[k] * W2[k * 2]; p1 += hsh[k] * W2[k * 2 + 1]; }
    float invp = 1.f / fmaxf(sqrtf(p0 * p0 + p1 * p1), 1e-12f);
    float q0 = p0 * invp, q1 = p1 * invp;
    const float PI2 = 6.2831853071795864769f;
    float ang = atan2f(q1, q0) + PI2;
    if (ang >= PI2) ang -= PI2;
    out[n * 2 + 0] = q0;
    out[n * 2 + 1] = q1;
    out[2 * NN + n] = ang;
    float n2 = q0 * q0 * stats_s[0] + q1 * q1 * stats_s[1] +
               2.f * q0 * q1 * stats_s[2] +
               2.f * q0 * stats_s[3] + 2.f * q1 * stats_s[4] + stats_s[5];
    qsh[0] = q0;
    qsh[1] = q1;
    qsh[2] = 1.f / fmaxf(sqrtf(n2), 1e-12f);
  }
  __syncthreads();
  const float q0 = qsh[0], q1 = qsh[1], inv = qsh[2];

  float* orec = out + 3 * NN + (size_t)n * GG;
  for (int i = t; i < GG / 4; i += 256) {
    float4 w0 = *(const float4*)&Wdec[i * 4];
    float4 w1 = *(const float4*)&Wdec[GG + i * 4];
    float4 b4 = *(const float4*)&bdec[i * 4];
    float4 o;
    o.x = (q0 * w0.x + q1 * w1.x + b4.x) * inv;
    o.y = (q0 * w0.y + q1 * w1.y + b4.y) * inv;
    o.z = (q0 * w0.z + q1 * w1.z + b4.z) * inv;
    o.w = (q0 * w0.w + q1 * w1.w + b4.w) * inv;
    *(float4*)&orec[i * 4] = o;
  }
}

// ---------------------------------------------------------------------------
extern "C" void kernel_launch(void* const* d_in, const int* in_sizes, int n_in,
                              void* d_out, int out_size, void* d_ws, size_t ws_size,
                              hipStream_t stream) {
  (void)in_sizes; (void)n_in; (void)out_size; (void)d_ws; (void)ws_size;
  const float* x    = (const float*)d_in[0];
  const int*   tidx = (const int*)  d_in[1];
  const int*   pidx = (const int*)  d_in[2];
  const float* Wp   = (const float*)d_in[3];
  const float* bp   = (const float*)d_in[4];
  const float* tt   = (const float*)d_in[5];
  const float* W1   = (const float*)d_in[6];
  const float* b1   = (const float*)d_in[7];
  const float* W2   = (const float*)d_in[8];
  const float* b2   = (const float*)d_in[9];
  const float* Wdec = (const float*)d_in[10];
  const float* bdec = (const float*)d_in[11];
  float* out = (float*)d_out;

  dim3 gridT((GG + 127) / 128, NN / 128, 1);   // 157 x 16
  transpose_convert_kernel<<<gridT, 256, 0, stream>>>(x);
  wconvert_kernel<<<(PP * 16384) / 256, 256, 0, stream>>>(Wp);
  wdec_stats_partial<<<64, 256, 0, stream>>>(Wdec, bdec);

  dim3 gridA(NN / TN, NOCT, 1);                // 16 x 25
  proj_mfma_kernel<<<gridA, 512, 0, stream>>>(tidx, pidx, bp, tt);

  combine_rec_kernel<<<NN, 256, 0, stream>>>(W1, b1, W2, b2, Wdec, bdec, out);
}